// Round 6
// baseline (215.284 us; speedup 1.0000x reference)
//
#include <hip/hip_runtime.h>
#include <math.h>
#include <limits.h>

#define NEV 100000
#define NB 8
#define NSL 32                   // event slices per batch for binning
#define SLEV (NEV / NSL)         // 3125
#define CAP 4096                 // bin region capacity (expect 3125, +16 sigma)
#define F32EPS 1.1920929e-7f
#define SCALE 524288.0f          // 2^19 fixed-point for num
#define INV_SCALE (1.0f/524288.0f)

typedef unsigned long long u64;
typedef unsigned int u32;

// ws layout (bytes):
//   0           bins:  uint2[8*32 regions][4096]     8,388,608
//   8,388,608   cursors: int[256]                    1,024     } zeroed together
//   8,389,632   trefMax: u32[16]   (bm = b*2+m)      64        } (memset 0)
//   8,389,696   trefMin: u32[16]                     64          (memset 0xFF)
//   8,389,760   fi0P: u64[16bm*2dir][8 slice][1024]  2,097,152
//   10,486,912  fi1P: u64[16bm*2dir][8 slice][4096]  8,388,608
#define OFF_CURS  8388608
#define OFF_TMAX  8389632
#define OFF_TMIN  8389696
#define OFF_FI0P  8389760
#define OFF_FI1P  10486912

__device__ __forceinline__ void lds_add64(u64* p, u64 v) {
    __hip_atomic_fetch_add(p, v, __ATOMIC_RELAXED, __HIP_MEMORY_SCOPE_WORKGROUP);
}
__device__ __forceinline__ int lds_add32(int* p, int v) {
    return __hip_atomic_fetch_add(p, v, __ATOMIC_RELAXED, __HIP_MEMORY_SCOPE_WORKGROUP);
}

// =============== fused binning: hist + atomic-offset + scatter + tref ===============
// 256 blocks x 256 threads; bid = sl*8 + b
__global__ __launch_bounds__(256) void k_bin2(
    const int* __restrict__ xs, const int* __restrict__ ys,
    const float* __restrict__ ts, const int* __restrict__ ps,
    int* __restrict__ cursors, u32* __restrict__ trefMin, u32* __restrict__ trefMax,
    uint2* __restrict__ bins) {
    int bid = blockIdx.x;
    int b = bid & 7;
    int sl = bid >> 3;
    int tid = threadIdx.x;
    int w = tid >> 6, lane = tid & 63;

    const int*   xb = xs + b * NEV + sl * SLEV;
    const int*   yb = ys + b * NEV + sl * SLEV;
    const float* tb = ts + b * NEV + sl * SLEV;
    const int*   pb = ps + b * NEV + sl * SLEV;

    __shared__ int hist[4][32];
    __shared__ int curs[4][32];
    if (tid < 128) hist[tid >> 5][tid & 31] = 0;
    __syncthreads();

    float mnP = 2.0f, mxP = -1.0f, mnN = 2.0f, mxN = -1.0f;
    for (int i = w * 64 + lane; i < SLEV; i += 256) {
        int p = pb[i];
        int y = yb[i];
        float t = tb[i];
        int m = (p == 1) ? 0 : 1;
        lds_add32(&hist[w][m * 16 + (y >> 4)], 1);
        if (m == 0) { mnP = fminf(mnP, t); mxP = fmaxf(mxP, t); }
        else        { mnN = fminf(mnN, t); mxN = fmaxf(mxN, t); }
    }
    for (int o = 32; o > 0; o >>= 1) {
        mnP = fminf(mnP, __shfl_down(mnP, o, 64));
        mxP = fmaxf(mxP, __shfl_down(mxP, o, 64));
        mnN = fminf(mnN, __shfl_down(mnN, o, 64));
        mxN = fmaxf(mxN, __shfl_down(mxN, o, 64));
    }
    if (lane == 0) {
        if (mxP >= 0.0f) {
            atomicMin(&trefMin[b * 2 + 0], __float_as_uint(mnP));
            atomicMax(&trefMax[b * 2 + 0], __float_as_uint(mxP));
        }
        if (mxN >= 0.0f) {
            atomicMin(&trefMin[b * 2 + 1], __float_as_uint(mnN));
            atomicMax(&trefMax[b * 2 + 1], __float_as_uint(mxN));
        }
    }
    __syncthreads();
    if (tid < 32) {
        int tot = hist[0][tid] + hist[1][tid] + hist[2][tid] + hist[3][tid];
        int base = atomicAdd(&cursors[b * 32 + tid], tot);  // device-scope
        int run = base;
        #pragma unroll
        for (int w2 = 0; w2 < 4; ++w2) { curs[w2][tid] = run; run += hist[w2][tid]; }
    }
    __syncthreads();
    for (int i = w * 64 + lane; i < SLEV; i += 256) {
        int p = pb[i];
        int x = xb[i];
        int y = yb[i];
        float t = tb[i];
        int m = (p == 1) ? 0 : 1;
        int bin = m * 16 + (y >> 4);
        int off = lds_add32(&curs[w][bin], 1);
        if (off < CAP)
            bins[(size_t)(b * 32 + bin) * CAP + off] =
                make_uint2((u32)(x | (y << 8)), __float_as_uint(t));
    }
}

// =============== event splat, dir-split, <=32KB LDS ===============
// 1536 blocks x 512 thr: b=bid&7; r=bid>>3 (0..191): m=r&1, dir=(r>>1)&1, role=r>>2 (0..47)
//   role 0..7  : fi0 bin-slice s: bins {s, s+8}; 4 LDS replicas of 32x32; partial -> fi0P
//   role 8..15 : fi1 bin-slice s: bins {s, s+8}; 64x64 grid; partial -> fi1P
//   role 16..31: fi2 chunk c: rows [8c,8c+8) of 128; bins c-1..c+1; finalize
//   role 32..47: fi3 chunk c: rows [16c,16c+16) of 256; bins c-1..c+1; finalize
// max vertical displacement |t_*fy| <~5.3 rows < 8 (fi2) / 16 (fi3) halo.
__global__ __launch_bounds__(512) void k_splat2(
    const float* __restrict__ f0, const float* __restrict__ f1,
    const float* __restrict__ f2, const float* __restrict__ f3,
    const uint2* __restrict__ bins, const int* __restrict__ cursors,
    const u32* __restrict__ trefMin, const u32* __restrict__ trefMax,
    u64* __restrict__ fi0P, u64* __restrict__ fi1P,
    float* __restrict__ out) {
    __shared__ u64 acc[4096];   // 32 KB
    __shared__ float red[8];

    int tid = threadIdx.x;
    int bid = blockIdx.x;
    int b = bid & 7;
    int r = bid >> 3;
    int m = r & 1;
    int dir = (r >> 1) & 1;
    int role = r >> 2;
    int bm = b * 2 + m;

    int fi, row0 = 0, nrows, lo, hi, slice = 0, mode;
    if (role < 8)       { fi = 0; mode = 0; slice = role;      nrows = 32; lo = -1; hi = -1; }
    else if (role < 16) { fi = 1; mode = 0; slice = role - 8;  nrows = 64; lo = -1; hi = -1; }
    else if (role < 32) { int c = role - 16; fi = 2; mode = 1; row0 = 8 * c;  nrows = 8;
                          lo = max(0, c - 1); hi = min(15, c + 1); }
    else                { int c = role - 32; fi = 3; mode = 1; row0 = 16 * c; nrows = 16;
                          lo = max(0, c - 1); hi = min(15, c + 1); }

    int W = 32 << fi;
    int sh = 3 - fi;
    int rowEnd = row0 + nrows;
    float Wm1 = (float)(W - 1);
    int usedN = (fi == 2) ? 1024 : 4096;

    const float* flow = (fi == 0) ? f0 : (fi == 1) ? f1 : (fi == 2) ? f2 : f3;
    const float* fxp = flow + (size_t)b * 2 * W * W;
    const float* fyp = fxp + W * W;

    for (int i = tid; i < usedN; i += 512) acc[i] = 0ULL;
    __syncthreads();

    float trF = __uint_as_float(trefMax[bm]);
    float trB = __uint_as_float(trefMin[bm]);

    int rep = (fi == 0) ? (((tid >> 4) & 3) << 10) : 0;

    // bin list
    int blist[3];
    int nb;
    if (mode == 0) { nb = 2; blist[0] = slice; blist[1] = slice + 8; }
    else { nb = hi - lo + 1; for (int q = 0; q < nb; ++q) blist[q] = lo + q; }

    for (int q = 0; q < nb; ++q) {
        int region = b * 32 + m * 16 + blist[q];
        int cnt = min(cursors[region], CAP);
        const uint2* eb = bins + (size_t)region * CAP;
        for (int i = tid; i < cnt; i += 512) {
            uint2 ev = eb[i];
            int x = ev.x & 255;
            int y = (ev.x >> 8) & 255;
            float t = __uint_as_float(ev.y);
            int xi = x >> sh, yi = y >> sh;
            float fx = fxp[yi * W + xi];
            float fy = fyp[yi * W + xi];
            float t_ = dir ? (trB - t - F32EPS) : (trF - t + F32EPS);
            float x_ = fminf(fmaxf((float)xi + t_ * fx, 0.0f), Wm1);
            float y_ = fminf(fmaxf((float)yi + t_ * fy, 0.0f), Wm1);
            float x0f = floorf(x_), y0f = floorf(y_);
            float x0w = x_ - x0f, x1w = 1.0f - x0w;
            float y0w = y_ - y0f, y1w = 1.0f - y0w;
            int x0i = (int)x0f, y0i = (int)y0f;
            int x1i = min(x0i + 1, W - 1);
            int y1i = min(y0i + 1, W - 1);
            u64 Pa = (1ULL << 32) | (u64)(u32)(x0w * y0w * t * SCALE);  // (x1i,y1i)
            u64 Pb = (1ULL << 32) | (u64)(u32)(x1w * y0w * t * SCALE);  // (x0i,y1i)
            u64 Pc = (1ULL << 32) | (u64)(u32)(x0w * y1w * t * SCALE);  // (x1i,y0i)
            u64 Pd = (1ULL << 32) | (u64)(u32)(x1w * y1w * t * SCALE);  // (x0i,y0i)
            if (y1i >= row0 && y1i < rowEnd) {
                int rr = rep + (y1i - row0) * W;
                lds_add64(&acc[rr + x1i], Pa);
                lds_add64(&acc[rr + x0i], Pb);
            }
            if (y0i >= row0 && y0i < rowEnd) {
                int rr = rep + (y0i - row0) * W;
                lds_add64(&acc[rr + x1i], Pc);
                lds_add64(&acc[rr + x0i], Pd);
            }
        }
    }
    __syncthreads();

    if (mode == 0) {
        int g = bm * 2 + dir;
        if (fi == 0) {
            for (int j = tid; j < 1024; j += 512)
                fi0P[(size_t)(g * 8 + slice) * 1024 + j] =
                    acc[j] + acc[j + 1024] + acc[j + 2048] + acc[j + 3072];
        } else {
            for (int j = tid; j < 4096; j += 512)
                fi1P[(size_t)(g * 8 + slice) * 4096 + j] = acc[j];
        }
        return;
    }

    float s = 0.0f;
    for (int j = tid; j < usedN; j += 512) {
        u64 v = acc[j];
        float num = (float)(u32)(v & 0xffffffffULL) * INV_SCALE;
        float den = (float)(u32)(v >> 32);
        float rr = num / (den + F32EPS);
        s += sqrtf(rr * rr + 1e-6f);
    }
    for (int o = 32; o > 0; o >>= 1) s += __shfl_down(s, o, 64);
    if ((tid & 63) == 0) red[tid >> 6] = s;
    __syncthreads();
    if (tid == 0) {
        float tot = 0.0f;
        for (int w2 = 0; w2 < 8; ++w2) tot += red[w2];
        atomicAdd(out, tot);
    }
}

// =============== tail: merge fi0/fi1 partials + weight decay + smoothness ===============
// 640 blocks x 256 threads (= 163,840 threads, one per merge cell)
__global__ __launch_bounds__(256) void k_tail(
    const u64* __restrict__ fi0P, const u64* __restrict__ fi1P,
    const float* __restrict__ params, int nP,
    const float* __restrict__ f0, const float* __restrict__ f1,
    const float* __restrict__ f2, const float* __restrict__ f3,
    float* __restrict__ out) {
    int gtid = blockIdx.x * 256 + threadIdx.x;
    int gstride = gridDim.x * 256;
    float s = 0.0f;

    // merge: fi0 -> 32 grids x 1024 cells; fi1 -> 32 grids x 4096 cells
    {
        u64 v = 0;
        if (gtid < 32768) {
            int g = gtid >> 10, j = gtid & 1023;
            const u64* p = fi0P + (size_t)(g * 8) * 1024 + j;
            #pragma unroll
            for (int k = 0; k < 8; ++k) v += p[k * 1024];
        } else {
            int rr = gtid - 32768;
            int g = rr >> 12, j = rr & 4095;
            const u64* p = fi1P + (size_t)(g * 8) * 4096 + j;
            #pragma unroll
            for (int k = 0; k < 8; ++k) v += p[k * 4096];
        }
        float num = (float)(u32)(v & 0xffffffffULL) * INV_SCALE;
        float den = (float)(u32)(v >> 32);
        float rr = num / (den + F32EPS);
        s += sqrtf(rr * rr + 1e-6f);
    }

    // weight decay
    int n4 = nP >> 2;
    const float4* p4 = (const float4*)params;
    float wsum = 0.0f;
    for (int i = gtid; i < n4; i += gstride) {
        float4 v = p4[i];
        wsum += v.x * v.x + v.y * v.y + v.z * v.z + v.w * v.w;
    }
    if (gtid == 0) for (int i = n4 * 4; i < nP; ++i) wsum += params[i] * params[i];
    s += wsum * 5e-5f;

    // smoothness
    const int nTot = 1392640;
    for (int idx = gtid; idx < nTot; idx += gstride) {
        int fi, off, logW;
        if (idx < 16384)       { fi = 0; off = 0;      logW = 5; }
        else if (idx < 81920)  { fi = 1; off = 16384;  logW = 6; }
        else if (idx < 344064) { fi = 2; off = 81920;  logW = 7; }
        else                   { fi = 3; off = 344064; logW = 8; }
        const float* f = (fi == 0) ? f0 : (fi == 1) ? f1 : (fi == 2) ? f2 : f3;
        int W = 1 << logW;
        int local = idx - off;
        int x = local & (W - 1);
        int y = (local >> logW) & (W - 1);
        float c_lr = 6.25f / (float)(16 * W * (W - 1));
        float c_dd = 6.25f / (float)(16 * (W - 1) * (W - 1));
        float v = f[local];
        bool xok = x < W - 1;
        bool yok = y < W - 1;
        float vr = xok ? f[local + 1] : 0.0f;
        float vd = yok ? f[local + W] : 0.0f;
        if (xok) { float d = vr - v; s += c_lr * __powf(d * d + 1e-6f, 0.45f); }
        if (yok) { float d = vd - v; s += c_lr * __powf(d * d + 1e-6f, 0.45f); }
        if (xok && yok) {
            float d1 = f[local + W + 1] - v;
            s += c_dd * __powf(d1 * d1 + 1e-6f, 0.45f);
            float d2 = vr - vd;
            s += c_dd * __powf(d2 * d2 + 1e-6f, 0.45f);
        }
    }

    for (int o = 32; o > 0; o >>= 1) s += __shfl_down(s, o, 64);
    __shared__ float red[4];
    if ((threadIdx.x & 63) == 0) red[threadIdx.x >> 6] = s;
    __syncthreads();
    if (threadIdx.x == 0)
        atomicAdd(out, red[0] + red[1] + red[2] + red[3]);
}

extern "C" void kernel_launch(void* const* d_in, const int* in_sizes, int n_in,
                              void* d_out, int out_size, void* d_ws, size_t ws_size,
                              hipStream_t stream) {
    const float* f0 = (const float*)d_in[0];
    const float* f1 = (const float*)d_in[1];
    const float* f2 = (const float*)d_in[2];
    const float* f3 = (const float*)d_in[3];
    const int*   xs = (const int*)d_in[4];
    const int*   ys = (const int*)d_in[5];
    const float* ts = (const float*)d_in[6];
    const int*   ps = (const int*)d_in[7];
    const float* params = (const float*)d_in[10];
    float* out = (float*)d_out;

    char* ws = (char*)d_ws;
    uint2* bins    = (uint2*)ws;
    int*   cursors = (int*)(ws + OFF_CURS);
    u32*   trefMax = (u32*)(ws + OFF_TMAX);
    u32*   trefMin = (u32*)(ws + OFF_TMIN);
    u64*   fi0P    = (u64*)(ws + OFF_FI0P);
    u64*   fi1P    = (u64*)(ws + OFF_FI1P);

    // zero cursors + trefMax (contiguous 1088 B); trefMin -> 0xFF; out -> 0
    hipMemsetAsync(ws + OFF_CURS, 0, 1024 + 64, stream);
    hipMemsetAsync(ws + OFF_TMIN, 0xFF, 64, stream);
    hipMemsetAsync(d_out, 0, 4, stream);

    hipLaunchKernelGGL(k_bin2, dim3(NB * NSL), dim3(256), 0, stream,
                       xs, ys, ts, ps, cursors, trefMin, trefMax, bins);
    hipLaunchKernelGGL(k_splat2, dim3(1536), dim3(512), 0, stream,
                       f0, f1, f2, f3, bins, cursors, trefMin, trefMax,
                       fi0P, fi1P, out);
    hipLaunchKernelGGL(k_tail, dim3(640), dim3(256), 0, stream,
                       fi0P, fi1P, params, in_sizes[10], f0, f1, f2, f3, out);
}

// Round 7
// 214.436 us; speedup vs baseline: 1.0040x; 1.0040x over previous
//
#include <hip/hip_runtime.h>
#include <math.h>
#include <limits.h>

#define NEV 100000
#define NB 8
#define NSL 32                   // event slices per batch for binning
#define SLEV (NEV / NSL)         // 3125
#define CAP 4096                 // bin region capacity (expect ~3125)
#define F32EPS 1.1920929e-7f
#define SCALE 524288.0f          // 2^19 fixed-point for num
#define INV_SCALE (1.0f/524288.0f)

typedef unsigned long long u64;
typedef unsigned int u32;

// ws layout (bytes):
//   0           bins:  uint2[8*32 regions][4096]       8,388,608
//   8,388,608   cursors: int[256]                      1,024   } memset 0 together
//   8,389,632   trefMax: u32[16]  (bm = b*2+m)         64      }
//   8,389,696   trefMin: u32[16]                       64        memset 0xFF
//   8,389,760   flowI: float2[696,320]                 5,570,560
//   13,960,320  fi0P: u64[32 g][8 sl][1024]            2,097,152
//   16,057,472  fi1P: u64[32 g][8 sl][4096]            8,388,608
#define OFF_CURS  8388608
#define OFF_TMAX  8389632
#define OFF_TMIN  8389696
#define OFF_FLOWI 8389760
#define OFF_FI0P  13960320
#define OFF_FI1P  16057472

// flowI float2-offsets per fi: fi0: 0 + b*1024; fi1: 8192 + b*4096;
// fi2: 40960 + b*16384; fi3: 172032 + b*65536. total 696,320.

__device__ __forceinline__ void lds_add64(u64* p, u64 v) {
    __hip_atomic_fetch_add(p, v, __ATOMIC_RELAXED, __HIP_MEMORY_SCOPE_WORKGROUP);
}
__device__ __forceinline__ int lds_add32(int* p, int v) {
    return __hip_atomic_fetch_add(p, v, __ATOMIC_RELAXED, __HIP_MEMORY_SCOPE_WORKGROUP);
}

// =============== prep: binning (0..255) + flow transpose (256..319) + misc (320..511) ===============
__global__ __launch_bounds__(256) void k_prep(
    const int* __restrict__ xs, const int* __restrict__ ys,
    const float* __restrict__ ts, const int* __restrict__ ps,
    const float* __restrict__ f0, const float* __restrict__ f1,
    const float* __restrict__ f2, const float* __restrict__ f3,
    const float* __restrict__ params, int nP,
    int* __restrict__ cursors, u32* __restrict__ trefMin, u32* __restrict__ trefMax,
    uint2* __restrict__ bins, float2* __restrict__ flowI, float* __restrict__ out) {
    int bid = blockIdx.x;
    int tid = threadIdx.x;

    if (bid < 256) {
        // ---- binning ----
        int b = bid & 7;
        int sl = bid >> 3;
        int w = tid >> 6, lane = tid & 63;

        const int*   xb = xs + b * NEV + sl * SLEV;
        const int*   yb = ys + b * NEV + sl * SLEV;
        const float* tb = ts + b * NEV + sl * SLEV;
        const int*   pb = ps + b * NEV + sl * SLEV;

        __shared__ int hist[4][32];
        __shared__ int curs[4][32];
        if (tid < 128) hist[tid >> 5][tid & 31] = 0;
        __syncthreads();

        float mnP = 2.0f, mxP = -1.0f, mnN = 2.0f, mxN = -1.0f;
        for (int i = w * 64 + lane; i < SLEV; i += 256) {
            int p = pb[i];
            int y = yb[i];
            float t = tb[i];
            int m = (p == 1) ? 0 : 1;
            lds_add32(&hist[w][m * 16 + (y >> 4)], 1);
            if (m == 0) { mnP = fminf(mnP, t); mxP = fmaxf(mxP, t); }
            else        { mnN = fminf(mnN, t); mxN = fmaxf(mxN, t); }
        }
        for (int o = 32; o > 0; o >>= 1) {
            mnP = fminf(mnP, __shfl_down(mnP, o, 64));
            mxP = fmaxf(mxP, __shfl_down(mxP, o, 64));
            mnN = fminf(mnN, __shfl_down(mnN, o, 64));
            mxN = fmaxf(mxN, __shfl_down(mxN, o, 64));
        }
        if (lane == 0) {
            if (mxP >= 0.0f) {
                atomicMin(&trefMin[b * 2 + 0], __float_as_uint(mnP));
                atomicMax(&trefMax[b * 2 + 0], __float_as_uint(mxP));
            }
            if (mxN >= 0.0f) {
                atomicMin(&trefMin[b * 2 + 1], __float_as_uint(mnN));
                atomicMax(&trefMax[b * 2 + 1], __float_as_uint(mxN));
            }
        }
        __syncthreads();
        if (tid < 32) {
            int tot = hist[0][tid] + hist[1][tid] + hist[2][tid] + hist[3][tid];
            int base = atomicAdd(&cursors[b * 32 + tid], tot);  // device-scope
            int run = base;
            #pragma unroll
            for (int w2 = 0; w2 < 4; ++w2) { curs[w2][tid] = run; run += hist[w2][tid]; }
        }
        __syncthreads();
        for (int i = w * 64 + lane; i < SLEV; i += 256) {
            int p = pb[i];
            int x = xb[i];
            int y = yb[i];
            float t = tb[i];
            int m = (p == 1) ? 0 : 1;
            int bin = m * 16 + (y >> 4);
            int off = lds_add32(&curs[w][bin], 1);
            if (off < CAP)
                bins[(size_t)(b * 32 + bin) * CAP + off] =
                    make_uint2((u32)(x | (y << 8)), __float_as_uint(t));
        }
        return;
    }

    if (bid < 320) {
        // ---- flow transpose to interleaved float2 ----
        const int nTot = 696320;
        for (int idx = (bid - 256) * 256 + tid; idx < nTot; idx += 64 * 256) {
            const float* src; int n, base, local = idx;
            if (idx < 8192)        { src = f0; n = 1024;  base = 0;      }
            else if (idx < 40960)  { src = f1; n = 4096;  base = 8192;   local = idx - 8192; }
            else if (idx < 172032) { src = f2; n = 16384; base = 40960;  local = idx - 40960; }
            else                   { src = f3; n = 65536; base = 172032; local = idx - 172032; }
            int b = local / n;
            int i = local - b * n;
            float2 v;
            v.x = src[(size_t)b * 2 * n + i];
            v.y = src[(size_t)b * 2 * n + n + i];
            flowI[base + local] = v;
        }
        return;
    }

    // ---- weight decay + smoothness ----
    int gtid = (bid - 320) * 256 + tid;
    int gstride = 192 * 256;
    float s = 0.0f;

    int n4 = nP >> 2;
    const float4* p4 = (const float4*)params;
    float wsum = 0.0f;
    for (int i = gtid; i < n4; i += gstride) {
        float4 v = p4[i];
        wsum += v.x * v.x + v.y * v.y + v.z * v.z + v.w * v.w;
    }
    if (gtid == 0) for (int i = n4 * 4; i < nP; ++i) wsum += params[i] * params[i];
    s += wsum * 5e-5f;

    const int nTot = 1392640;
    for (int idx = gtid; idx < nTot; idx += gstride) {
        int fi, off, logW;
        if (idx < 16384)       { fi = 0; off = 0;      logW = 5; }
        else if (idx < 81920)  { fi = 1; off = 16384;  logW = 6; }
        else if (idx < 344064) { fi = 2; off = 81920;  logW = 7; }
        else                   { fi = 3; off = 344064; logW = 8; }
        const float* f = (fi == 0) ? f0 : (fi == 1) ? f1 : (fi == 2) ? f2 : f3;
        int W = 1 << logW;
        int local = idx - off;
        int x = local & (W - 1);
        int y = (local >> logW) & (W - 1);
        float c_lr = 6.25f / (float)(16 * W * (W - 1));
        float c_dd = 6.25f / (float)(16 * (W - 1) * (W - 1));
        float v = f[local];
        bool xok = x < W - 1;
        bool yok = y < W - 1;
        float vr = xok ? f[local + 1] : 0.0f;
        float vd = yok ? f[local + W] : 0.0f;
        if (xok) { float d = vr - v; s += c_lr * __powf(d * d + 1e-6f, 0.45f); }
        if (yok) { float d = vd - v; s += c_lr * __powf(d * d + 1e-6f, 0.45f); }
        if (xok && yok) {
            float d1 = f[local + W + 1] - v;
            s += c_dd * __powf(d1 * d1 + 1e-6f, 0.45f);
            float d2 = vr - vd;
            s += c_dd * __powf(d2 * d2 + 1e-6f, 0.45f);
        }
    }

    for (int o = 32; o > 0; o >>= 1) s += __shfl_down(s, o, 64);
    __shared__ float red[4];
    if ((tid & 63) == 0) red[tid >> 6] = s;
    __syncthreads();
    if (tid == 0)
        atomicAdd(out, red[0] + red[1] + red[2] + red[3]);
}

// =============== event splat, dir-split, 32 KB LDS, 1 gather/event ===============
// 1152 blocks x 512 thr: b=bid&7; r=bid>>3: m=r&1, dir=(r>>1)&1, role=r>>2 (0..35)
//   role 0..3  : fi2 chunk c (32 grid rows of 128), bins 4c-1..4c+4, finalize
//   role 4..19 : fi3 chunk c (16 grid rows of 256), bins c-1..c+1, finalize
//   role 20..27: fi0 bin-slice s: bins {s,s+8}, 4 replicas of 32x32 -> partial fi0P
//   role 28..35: fi1 bin-slice s: bins {s,s+8}, 64x64 grid -> partial fi1P
// max vertical displacement |t_*fy| <= ~5.5 grid rows < all halos (8 / 16 rows).
__global__ __launch_bounds__(512) void k_splat2(
    const float2* __restrict__ flowI,
    const uint2* __restrict__ bins, const int* __restrict__ cursors,
    const u32* __restrict__ trefMin, const u32* __restrict__ trefMax,
    u64* __restrict__ fi0P, u64* __restrict__ fi1P,
    float* __restrict__ out) {
    __shared__ u64 acc[4096];   // 32 KB
    __shared__ float red[8];

    int tid = threadIdx.x;
    int bid = blockIdx.x;
    int b = bid & 7;
    int r = bid >> 3;
    int m = r & 1;
    int dir = (r >> 1) & 1;
    int role = r >> 2;
    int bm = b * 2 + m;

    int fi, row0 = 0, nrows = 0, lo = 0, hi = 0, slice = 0, mode;
    if (role < 4)       { int c = role;      fi = 2; mode = 1; row0 = 32 * c; nrows = 32;
                          lo = max(0, 4 * c - 1); hi = min(15, 4 * c + 4); }
    else if (role < 20) { int c = role - 4;  fi = 3; mode = 1; row0 = 16 * c; nrows = 16;
                          lo = max(0, c - 1); hi = min(15, c + 1); }
    else if (role < 28) { fi = 0; mode = 0; slice = role - 20; }
    else                { fi = 1; mode = 0; slice = role - 28; }

    int W = 32 << fi;
    int sh = 3 - fi;
    int rowEnd = row0 + nrows;
    float Wm1 = (float)(W - 1);

    int fiB = (fi == 0) ? b * 1024
            : (fi == 1) ? 8192 + b * 4096
            : (fi == 2) ? 40960 + b * 16384
                        : 172032 + b * 65536;

    for (int i = tid; i < 4096; i += 512) acc[i] = 0ULL;
    __syncthreads();

    float trX = dir ? __uint_as_float(trefMin[bm]) : __uint_as_float(trefMax[bm]);
    float epsA = dir ? -F32EPS : F32EPS;

    int rep = (fi == 0) ? (((tid >> 4) & 3) << 10) : 0;

    int blist[6];
    int nb;
    if (mode == 0) { nb = 2; blist[0] = slice; blist[1] = slice + 8; }
    else { nb = hi - lo + 1; for (int q = 0; q < nb; ++q) blist[q] = lo + q; }

    auto finish = [&](int xi, int yi, float t, float2 fv) {
        float t_ = trX - t + epsA;
        float x_ = fminf(fmaxf((float)xi + t_ * fv.x, 0.0f), Wm1);
        float y_ = fminf(fmaxf((float)yi + t_ * fv.y, 0.0f), Wm1);
        float x0f = floorf(x_), y0f = floorf(y_);
        float x0w = x_ - x0f, x1w = 1.0f - x0w;
        float y0w = y_ - y0f, y1w = 1.0f - y0w;
        int x0i = (int)x0f, y0i = (int)y0f;
        int x1i = min(x0i + 1, W - 1);
        int y1i = min(y0i + 1, W - 1);
        float tS = t * SCALE;
        u64 Pa = (1ULL << 32) | (u64)(u32)(x0w * y0w * tS);  // (x1i,y1i)
        u64 Pb = (1ULL << 32) | (u64)(u32)(x1w * y0w * tS);  // (x0i,y1i)
        u64 Pc = (1ULL << 32) | (u64)(u32)(x0w * y1w * tS);  // (x1i,y0i)
        u64 Pd = (1ULL << 32) | (u64)(u32)(x1w * y1w * tS);  // (x0i,y0i)
        if (mode == 0) {
            int r1 = rep + y1i * W;
            int r0 = rep + y0i * W;
            lds_add64(&acc[r1 + x1i], Pa);
            lds_add64(&acc[r1 + x0i], Pb);
            lds_add64(&acc[r0 + x1i], Pc);
            lds_add64(&acc[r0 + x0i], Pd);
        } else {
            if (y1i >= row0 && y1i < rowEnd) {
                int rr = (y1i - row0) * W;
                lds_add64(&acc[rr + x1i], Pa);
                lds_add64(&acc[rr + x0i], Pb);
            }
            if (y0i >= row0 && y0i < rowEnd) {
                int rr = (y0i - row0) * W;
                lds_add64(&acc[rr + x1i], Pc);
                lds_add64(&acc[rr + x0i], Pd);
            }
        }
    };

    for (int q = 0; q < nb; ++q) {
        int region = b * 32 + m * 16 + blist[q];
        int cnt = min(cursors[region], CAP);
        const uint2* eb = bins + (size_t)region * CAP;
        int i = tid;
        for (; i + 512 < cnt; i += 1024) {
            uint2 e1 = eb[i];
            uint2 e2 = eb[i + 512];
            int xi1 = (e1.x & 255) >> sh, yi1 = ((e1.x >> 8) & 255) >> sh;
            int xi2 = (e2.x & 255) >> sh, yi2 = ((e2.x >> 8) & 255) >> sh;
            float2 fv1 = flowI[fiB + yi1 * W + xi1];
            float2 fv2 = flowI[fiB + yi2 * W + xi2];
            finish(xi1, yi1, __uint_as_float(e1.y), fv1);
            finish(xi2, yi2, __uint_as_float(e2.y), fv2);
        }
        if (i < cnt) {
            uint2 e1 = eb[i];
            int xi1 = (e1.x & 255) >> sh, yi1 = ((e1.x >> 8) & 255) >> sh;
            float2 fv1 = flowI[fiB + yi1 * W + xi1];
            finish(xi1, yi1, __uint_as_float(e1.y), fv1);
        }
    }
    __syncthreads();

    if (mode == 0) {
        int g = bm * 2 + dir;
        if (fi == 0) {
            for (int j = tid; j < 1024; j += 512)
                fi0P[(size_t)(g * 8 + slice) * 1024 + j] =
                    acc[j] + acc[j + 1024] + acc[j + 2048] + acc[j + 3072];
        } else {
            for (int j = tid; j < 4096; j += 512)
                fi1P[(size_t)(g * 8 + slice) * 4096 + j] = acc[j];
        }
        return;
    }

    float s = 0.0f;
    for (int j = tid; j < 4096; j += 512) {
        u64 v = acc[j];
        float num = (float)(u32)(v & 0xffffffffULL) * INV_SCALE;
        float den = (float)(u32)(v >> 32);
        float rr = num / (den + F32EPS);
        s += sqrtf(rr * rr + 1e-6f);
    }
    for (int o = 32; o > 0; o >>= 1) s += __shfl_down(s, o, 64);
    if ((tid & 63) == 0) red[tid >> 6] = s;
    __syncthreads();
    if (tid == 0) {
        float tot = 0.0f;
        for (int w2 = 0; w2 < 8; ++w2) tot += red[w2];
        atomicAdd(out, tot);
    }
}

// =============== tail: merge fi0/fi1 partials ===============
// 640 blocks x 256 threads = 163,840 threads, one per cell
__global__ __launch_bounds__(256) void k_tail(
    const u64* __restrict__ fi0P, const u64* __restrict__ fi1P,
    float* __restrict__ out) {
    int gtid = blockIdx.x * 256 + threadIdx.x;
    u64 v = 0;
    if (gtid < 32768) {
        int g = gtid >> 10, j = gtid & 1023;
        const u64* p = fi0P + (size_t)(g * 8) * 1024 + j;
        #pragma unroll
        for (int k = 0; k < 8; ++k) v += p[k * 1024];
    } else {
        int rr = gtid - 32768;
        int g = rr >> 12, j = rr & 4095;
        const u64* p = fi1P + (size_t)(g * 8) * 4096 + j;
        #pragma unroll
        for (int k = 0; k < 8; ++k) v += p[k * 4096];
    }
    float num = (float)(u32)(v & 0xffffffffULL) * INV_SCALE;
    float den = (float)(u32)(v >> 32);
    float rr = num / (den + F32EPS);
    float s = sqrtf(rr * rr + 1e-6f);
    for (int o = 32; o > 0; o >>= 1) s += __shfl_down(s, o, 64);
    __shared__ float red[4];
    if ((threadIdx.x & 63) == 0) red[threadIdx.x >> 6] = s;
    __syncthreads();
    if (threadIdx.x == 0)
        atomicAdd(out, red[0] + red[1] + red[2] + red[3]);
}

extern "C" void kernel_launch(void* const* d_in, const int* in_sizes, int n_in,
                              void* d_out, int out_size, void* d_ws, size_t ws_size,
                              hipStream_t stream) {
    const float* f0 = (const float*)d_in[0];
    const float* f1 = (const float*)d_in[1];
    const float* f2 = (const float*)d_in[2];
    const float* f3 = (const float*)d_in[3];
    const int*   xs = (const int*)d_in[4];
    const int*   ys = (const int*)d_in[5];
    const float* ts = (const float*)d_in[6];
    const int*   ps = (const int*)d_in[7];
    const float* params = (const float*)d_in[10];
    float* out = (float*)d_out;

    char* ws = (char*)d_ws;
    uint2*  bins    = (uint2*)ws;
    int*    cursors = (int*)(ws + OFF_CURS);
    u32*    trefMax = (u32*)(ws + OFF_TMAX);
    u32*    trefMin = (u32*)(ws + OFF_TMIN);
    float2* flowI   = (float2*)(ws + OFF_FLOWI);
    u64*    fi0P    = (u64*)(ws + OFF_FI0P);
    u64*    fi1P    = (u64*)(ws + OFF_FI1P);

    hipMemsetAsync(ws + OFF_CURS, 0, 1024 + 64, stream);   // cursors + trefMax
    hipMemsetAsync(ws + OFF_TMIN, 0xFF, 64, stream);       // trefMin
    hipMemsetAsync(d_out, 0, 4, stream);

    hipLaunchKernelGGL(k_prep, dim3(512), dim3(256), 0, stream,
                       xs, ys, ts, ps, f0, f1, f2, f3, params, in_sizes[10],
                       cursors, trefMin, trefMax, bins, flowI, out);
    hipLaunchKernelGGL(k_splat2, dim3(1152), dim3(512), 0, stream,
                       flowI, bins, cursors, trefMin, trefMax, fi0P, fi1P, out);
    hipLaunchKernelGGL(k_tail, dim3(640), dim3(256), 0, stream, fi0P, fi1P, out);
}

// Round 8
// 193.525 us; speedup vs baseline: 1.1124x; 1.1081x over previous
//
#include <hip/hip_runtime.h>
#include <math.h>
#include <limits.h>

#define NEV 100000
#define NB 8
#define NSL 32                   // event slices per batch for binning
#define SLEV (NEV / NSL)         // 3125
#define CAP 4096                 // bin region capacity (expect ~3125)
#define F32EPS 1.1920929e-7f
#define SCALE 524288.0f          // 2^19 fixed-point for num
#define INV_SCALE (1.0f/524288.0f)

typedef unsigned long long u64;
typedef unsigned int u32;

// ws layout (bytes):
//   0           bins:  uint2[8*32 regions][4096]       8,388,608
//   8,388,608   cursors: int[256]                      1,024   } memset 0 together
//   8,389,632   trefMax: u32[16]  (bm = b*2+m)         64      }
//   8,389,696   trefMin: u32[16]                       64        memset 0xFF
//   8,389,760   flowI: float2[696,320]                 5,570,560
//   13,960,320  fi0P: u64[32 g][8 sl][1024]            2,097,152
//   16,057,472  fi1P: u64[32 g][8 sl][4096]            8,388,608
#define OFF_CURS  8388608
#define OFF_TMAX  8389632
#define OFF_TMIN  8389696
#define OFF_FLOWI 8389760
#define OFF_FI0P  13960320
#define OFF_FI1P  16057472

__device__ __forceinline__ void lds_add64(u64* p, u64 v) {
    __hip_atomic_fetch_add(p, v, __ATOMIC_RELAXED, __HIP_MEMORY_SCOPE_WORKGROUP);
}
__device__ __forceinline__ int lds_add32(int* p, int v) {
    return __hip_atomic_fetch_add(p, v, __ATOMIC_RELAXED, __HIP_MEMORY_SCOPE_WORKGROUP);
}

// =============== prep: binning (0..255) + flow transpose (256..319) ===============
__global__ __launch_bounds__(256) void k_prep(
    const int* __restrict__ xs, const int* __restrict__ ys,
    const float* __restrict__ ts, const int* __restrict__ ps,
    const float* __restrict__ f0, const float* __restrict__ f1,
    const float* __restrict__ f2, const float* __restrict__ f3,
    int* __restrict__ cursors, u32* __restrict__ trefMin, u32* __restrict__ trefMax,
    uint2* __restrict__ bins, float2* __restrict__ flowI) {
    int bid = blockIdx.x;
    int tid = threadIdx.x;

    if (bid < 256) {
        // ---- binning ----
        int b = bid & 7;
        int sl = bid >> 3;
        int w = tid >> 6, lane = tid & 63;

        const int*   xb = xs + b * NEV + sl * SLEV;
        const int*   yb = ys + b * NEV + sl * SLEV;
        const float* tb = ts + b * NEV + sl * SLEV;
        const int*   pb = ps + b * NEV + sl * SLEV;

        __shared__ int hist[4][32];
        __shared__ int curs[4][32];
        if (tid < 128) hist[tid >> 5][tid & 31] = 0;
        __syncthreads();

        float mnP = 2.0f, mxP = -1.0f, mnN = 2.0f, mxN = -1.0f;
        for (int i = w * 64 + lane; i < SLEV; i += 256) {
            int p = pb[i];
            int y = yb[i];
            float t = tb[i];
            int m = (p == 1) ? 0 : 1;
            lds_add32(&hist[w][m * 16 + (y >> 4)], 1);
            if (m == 0) { mnP = fminf(mnP, t); mxP = fmaxf(mxP, t); }
            else        { mnN = fminf(mnN, t); mxN = fmaxf(mxN, t); }
        }
        for (int o = 32; o > 0; o >>= 1) {
            mnP = fminf(mnP, __shfl_down(mnP, o, 64));
            mxP = fmaxf(mxP, __shfl_down(mxP, o, 64));
            mnN = fminf(mnN, __shfl_down(mnN, o, 64));
            mxN = fmaxf(mxN, __shfl_down(mxN, o, 64));
        }
        if (lane == 0) {
            if (mxP >= 0.0f) {
                atomicMin(&trefMin[b * 2 + 0], __float_as_uint(mnP));
                atomicMax(&trefMax[b * 2 + 0], __float_as_uint(mxP));
            }
            if (mxN >= 0.0f) {
                atomicMin(&trefMin[b * 2 + 1], __float_as_uint(mnN));
                atomicMax(&trefMax[b * 2 + 1], __float_as_uint(mxN));
            }
        }
        __syncthreads();
        if (tid < 32) {
            int tot = hist[0][tid] + hist[1][tid] + hist[2][tid] + hist[3][tid];
            int base = atomicAdd(&cursors[b * 32 + tid], tot);  // device-scope
            int run = base;
            #pragma unroll
            for (int w2 = 0; w2 < 4; ++w2) { curs[w2][tid] = run; run += hist[w2][tid]; }
        }
        __syncthreads();
        for (int i = w * 64 + lane; i < SLEV; i += 256) {
            int p = pb[i];
            int x = xb[i];
            int y = yb[i];
            float t = tb[i];
            int m = (p == 1) ? 0 : 1;
            int bin = m * 16 + (y >> 4);
            int off = lds_add32(&curs[w][bin], 1);
            if (off < CAP)
                bins[(size_t)(b * 32 + bin) * CAP + off] =
                    make_uint2((u32)(x | (y << 8)), __float_as_uint(t));
        }
        return;
    }

    // ---- flow transpose to interleaved float2 ----
    const int nTot = 696320;
    for (int idx = (bid - 256) * 256 + tid; idx < nTot; idx += 64 * 256) {
        const float* src; int n, base, local = idx;
        if (idx < 8192)        { src = f0; n = 1024;  base = 0;      }
        else if (idx < 40960)  { src = f1; n = 4096;  base = 8192;   local = idx - 8192; }
        else if (idx < 172032) { src = f2; n = 16384; base = 40960;  local = idx - 40960; }
        else                   { src = f3; n = 65536; base = 172032; local = idx - 172032; }
        int b = local / n;
        int i = local - b * n;
        float2 v;
        v.x = src[(size_t)b * 2 * n + i];
        v.y = src[(size_t)b * 2 * n + n + i];
        flowI[base + local] = v;
    }
}

// =============== splat + misc, one grid ===============
// 1344 blocks x 512 thr.
//   bid 0..191  : misc (weight decay + smoothness) — independent work filling bubbles
//   bid 192+    : splat: b=sb&7; r=sb>>3: m=r&1, dir=(r>>1)&1, role=r>>2 (0..35)
//     role 0..3  : fi2 chunk c (32 grid rows of 128), bins 4c-1..4c+4, finalize
//     role 4..19 : fi3 chunk c (16 grid rows of 256), bins c-1..c+1, finalize
//     role 20..27: fi0 bin-slice s: bins {s,s+8}, 4 replicas of 32x32 -> fi0P
//     role 28..35: fi1 bin-slice s: bins {s,s+8}, 64x64 grid -> fi1P
__global__ __launch_bounds__(512) void k_splat2(
    const float2* __restrict__ flowI,
    const uint2* __restrict__ bins, const int* __restrict__ cursors,
    const u32* __restrict__ trefMin, const u32* __restrict__ trefMax,
    const float* __restrict__ params, int nP,
    const float* __restrict__ f0, const float* __restrict__ f1,
    const float* __restrict__ f2, const float* __restrict__ f3,
    u64* __restrict__ fi0P, u64* __restrict__ fi1P,
    float* __restrict__ out) {
    __shared__ u64 acc[4096];   // 32 KB
    __shared__ float red[8];

    int tid = threadIdx.x;
    int bid = blockIdx.x;

    if (bid < 192) {
        // ---- misc: weight decay + smoothness ----
        int gtid = bid * 512 + tid;
        int gstride = 192 * 512;
        float s = 0.0f;

        int n4 = nP >> 2;
        const float4* p4 = (const float4*)params;
        float wsum = 0.0f;
        for (int i = gtid; i < n4; i += gstride) {
            float4 v = p4[i];
            wsum += v.x * v.x + v.y * v.y + v.z * v.z + v.w * v.w;
        }
        if (gtid == 0) for (int i = n4 * 4; i < nP; ++i) wsum += params[i] * params[i];
        s += wsum * 5e-5f;

        const int nTot = 1392640;
        for (int idx = gtid; idx < nTot; idx += gstride) {
            int fi, off, logW;
            if (idx < 16384)       { fi = 0; off = 0;      logW = 5; }
            else if (idx < 81920)  { fi = 1; off = 16384;  logW = 6; }
            else if (idx < 344064) { fi = 2; off = 81920;  logW = 7; }
            else                   { fi = 3; off = 344064; logW = 8; }
            const float* f = (fi == 0) ? f0 : (fi == 1) ? f1 : (fi == 2) ? f2 : f3;
            int W = 1 << logW;
            int local = idx - off;
            int x = local & (W - 1);
            int y = (local >> logW) & (W - 1);
            float c_lr = 6.25f / (float)(16 * W * (W - 1));
            float c_dd = 6.25f / (float)(16 * (W - 1) * (W - 1));
            float v = f[local];
            bool xok = x < W - 1;
            bool yok = y < W - 1;
            float vr = xok ? f[local + 1] : 0.0f;
            float vd = yok ? f[local + W] : 0.0f;
            if (xok) { float d = vr - v; s += c_lr * __powf(d * d + 1e-6f, 0.45f); }
            if (yok) { float d = vd - v; s += c_lr * __powf(d * d + 1e-6f, 0.45f); }
            if (xok && yok) {
                float d1 = f[local + W + 1] - v;
                s += c_dd * __powf(d1 * d1 + 1e-6f, 0.45f);
                float d2 = vr - vd;
                s += c_dd * __powf(d2 * d2 + 1e-6f, 0.45f);
            }
        }

        for (int o = 32; o > 0; o >>= 1) s += __shfl_down(s, o, 64);
        if ((tid & 63) == 0) red[tid >> 6] = s;
        __syncthreads();
        if (tid == 0) {
            float tot = 0.0f;
            for (int w2 = 0; w2 < 8; ++w2) tot += red[w2];
            atomicAdd(out, tot);
        }
        return;
    }

    int sb = bid - 192;
    int b = sb & 7;
    int r = sb >> 3;
    int m = r & 1;
    int dir = (r >> 1) & 1;
    int role = r >> 2;
    int bm = b * 2 + m;

    int fi, row0 = 0, nrows = 0, lo = 0, hi = 0, slice = 0, mode;
    if (role < 4)       { int c = role;      fi = 2; mode = 1; row0 = 32 * c; nrows = 32;
                          lo = max(0, 4 * c - 1); hi = min(15, 4 * c + 4); }
    else if (role < 20) { int c = role - 4;  fi = 3; mode = 1; row0 = 16 * c; nrows = 16;
                          lo = max(0, c - 1); hi = min(15, c + 1); }
    else if (role < 28) { fi = 0; mode = 0; slice = role - 20; }
    else                { fi = 1; mode = 0; slice = role - 28; }

    int W = 32 << fi;
    int sh = 3 - fi;
    int rowEnd = row0 + nrows;
    float Wm1 = (float)(W - 1);

    int fiB = (fi == 0) ? b * 1024
            : (fi == 1) ? 8192 + b * 4096
            : (fi == 2) ? 40960 + b * 16384
                        : 172032 + b * 65536;

    for (int i = tid; i < 4096; i += 512) acc[i] = 0ULL;
    __syncthreads();

    float trX = dir ? __uint_as_float(trefMin[bm]) : __uint_as_float(trefMax[bm]);
    float epsA = dir ? -F32EPS : F32EPS;

    int rep = (fi == 0) ? (((tid >> 4) & 3) << 10) : 0;

    int blist[6];
    int nb;
    if (mode == 0) { nb = 2; blist[0] = slice; blist[1] = slice + 8; }
    else { nb = hi - lo + 1; for (int q = 0; q < nb; ++q) blist[q] = lo + q; }

    auto finish = [&](int xi, int yi, float t, float2 fv) {
        float t_ = trX - t + epsA;
        float x_ = fminf(fmaxf((float)xi + t_ * fv.x, 0.0f), Wm1);
        float y_ = fminf(fmaxf((float)yi + t_ * fv.y, 0.0f), Wm1);
        float x0f = floorf(x_), y0f = floorf(y_);
        float x0w = x_ - x0f, x1w = 1.0f - x0w;
        float y0w = y_ - y0f, y1w = 1.0f - y0w;
        int x0i = (int)x0f, y0i = (int)y0f;
        int x1i = min(x0i + 1, W - 1);
        int y1i = min(y0i + 1, W - 1);
        float tS = t * SCALE;
        u64 Pa = (1ULL << 32) | (u64)(u32)(x0w * y0w * tS);  // (x1i,y1i)
        u64 Pb = (1ULL << 32) | (u64)(u32)(x1w * y0w * tS);  // (x0i,y1i)
        u64 Pc = (1ULL << 32) | (u64)(u32)(x0w * y1w * tS);  // (x1i,y0i)
        u64 Pd = (1ULL << 32) | (u64)(u32)(x1w * y1w * tS);  // (x0i,y0i)
        if (mode == 0) {
            int r1 = rep + y1i * W;
            int r0 = rep + y0i * W;
            lds_add64(&acc[r1 + x1i], Pa);
            lds_add64(&acc[r1 + x0i], Pb);
            lds_add64(&acc[r0 + x1i], Pc);
            lds_add64(&acc[r0 + x0i], Pd);
        } else {
            if (y1i >= row0 && y1i < rowEnd) {
                int rr = (y1i - row0) * W;
                lds_add64(&acc[rr + x1i], Pa);
                lds_add64(&acc[rr + x0i], Pb);
            }
            if (y0i >= row0 && y0i < rowEnd) {
                int rr = (y0i - row0) * W;
                lds_add64(&acc[rr + x1i], Pc);
                lds_add64(&acc[rr + x0i], Pd);
            }
        }
    };

    for (int q = 0; q < nb; ++q) {
        int region = b * 32 + m * 16 + blist[q];
        int cnt = min(cursors[region], CAP);
        const uint2* eb = bins + (size_t)region * CAP;
        int i = tid;
        for (; i + 512 < cnt; i += 1024) {
            uint2 e1 = eb[i];
            uint2 e2 = eb[i + 512];
            int xi1 = (e1.x & 255) >> sh, yi1 = ((e1.x >> 8) & 255) >> sh;
            int xi2 = (e2.x & 255) >> sh, yi2 = ((e2.x >> 8) & 255) >> sh;
            float2 fv1 = flowI[fiB + yi1 * W + xi1];
            float2 fv2 = flowI[fiB + yi2 * W + xi2];
            finish(xi1, yi1, __uint_as_float(e1.y), fv1);
            finish(xi2, yi2, __uint_as_float(e2.y), fv2);
        }
        if (i < cnt) {
            uint2 e1 = eb[i];
            int xi1 = (e1.x & 255) >> sh, yi1 = ((e1.x >> 8) & 255) >> sh;
            float2 fv1 = flowI[fiB + yi1 * W + xi1];
            finish(xi1, yi1, __uint_as_float(e1.y), fv1);
        }
    }
    __syncthreads();

    if (mode == 0) {
        int g = bm * 2 + dir;
        if (fi == 0) {
            for (int j = tid; j < 1024; j += 512)
                fi0P[(size_t)(g * 8 + slice) * 1024 + j] =
                    acc[j] + acc[j + 1024] + acc[j + 2048] + acc[j + 3072];
        } else {
            for (int j = tid; j < 4096; j += 512)
                fi1P[(size_t)(g * 8 + slice) * 4096 + j] = acc[j];
        }
        return;
    }

    float s = 0.0f;
    for (int j = tid; j < 4096; j += 512) {
        u64 v = acc[j];
        float num = (float)(u32)(v & 0xffffffffULL) * INV_SCALE;
        float den = (float)(u32)(v >> 32);
        float rr = num / (den + F32EPS);
        s += sqrtf(rr * rr + 1e-6f);
    }
    for (int o = 32; o > 0; o >>= 1) s += __shfl_down(s, o, 64);
    if ((tid & 63) == 0) red[tid >> 6] = s;
    __syncthreads();
    if (tid == 0) {
        float tot = 0.0f;
        for (int w2 = 0; w2 < 8; ++w2) tot += red[w2];
        atomicAdd(out, tot);
    }
}

// =============== tail: merge fi0/fi1 partials ===============
__global__ __launch_bounds__(256) void k_tail(
    const u64* __restrict__ fi0P, const u64* __restrict__ fi1P,
    float* __restrict__ out) {
    int gtid = blockIdx.x * 256 + threadIdx.x;
    u64 v = 0;
    if (gtid < 32768) {
        int g = gtid >> 10, j = gtid & 1023;
        const u64* p = fi0P + (size_t)(g * 8) * 1024 + j;
        #pragma unroll
        for (int k = 0; k < 8; ++k) v += p[k * 1024];
    } else {
        int rr = gtid - 32768;
        int g = rr >> 12, j = rr & 4095;
        const u64* p = fi1P + (size_t)(g * 8) * 4096 + j;
        #pragma unroll
        for (int k = 0; k < 8; ++k) v += p[k * 4096];
    }
    float num = (float)(u32)(v & 0xffffffffULL) * INV_SCALE;
    float den = (float)(u32)(v >> 32);
    float rr = num / (den + F32EPS);
    float s = sqrtf(rr * rr + 1e-6f);
    for (int o = 32; o > 0; o >>= 1) s += __shfl_down(s, o, 64);
    __shared__ float red[4];
    if ((threadIdx.x & 63) == 0) red[threadIdx.x >> 6] = s;
    __syncthreads();
    if (threadIdx.x == 0)
        atomicAdd(out, red[0] + red[1] + red[2] + red[3]);
}

extern "C" void kernel_launch(void* const* d_in, const int* in_sizes, int n_in,
                              void* d_out, int out_size, void* d_ws, size_t ws_size,
                              hipStream_t stream) {
    const float* f0 = (const float*)d_in[0];
    const float* f1 = (const float*)d_in[1];
    const float* f2 = (const float*)d_in[2];
    const float* f3 = (const float*)d_in[3];
    const int*   xs = (const int*)d_in[4];
    const int*   ys = (const int*)d_in[5];
    const float* ts = (const float*)d_in[6];
    const int*   ps = (const int*)d_in[7];
    const float* params = (const float*)d_in[10];
    float* out = (float*)d_out;

    char* ws = (char*)d_ws;
    uint2*  bins    = (uint2*)ws;
    int*    cursors = (int*)(ws + OFF_CURS);
    u32*    trefMax = (u32*)(ws + OFF_TMAX);
    u32*    trefMin = (u32*)(ws + OFF_TMIN);
    float2* flowI   = (float2*)(ws + OFF_FLOWI);
    u64*    fi0P    = (u64*)(ws + OFF_FI0P);
    u64*    fi1P    = (u64*)(ws + OFF_FI1P);

    hipMemsetAsync(ws + OFF_CURS, 0, 1024 + 64, stream);   // cursors + trefMax
    hipMemsetAsync(ws + OFF_TMIN, 0xFF, 64, stream);       // trefMin
    hipMemsetAsync(d_out, 0, 4, stream);

    hipLaunchKernelGGL(k_prep, dim3(320), dim3(256), 0, stream,
                       xs, ys, ts, ps, f0, f1, f2, f3,
                       cursors, trefMin, trefMax, bins, flowI);
    hipLaunchKernelGGL(k_splat2, dim3(1344), dim3(512), 0, stream,
                       flowI, bins, cursors, trefMin, trefMax,
                       params, in_sizes[10], f0, f1, f2, f3,
                       fi0P, fi1P, out);
    hipLaunchKernelGGL(k_tail, dim3(640), dim3(256), 0, stream, fi0P, fi1P, out);
}

// Round 9
// 188.991 us; speedup vs baseline: 1.1391x; 1.0240x over previous
//
#include <hip/hip_runtime.h>
#include <math.h>
#include <limits.h>

#define NEV 100000
#define NB 8
#define NSL 32                   // event slices per batch for binning
#define SLEV (NEV / NSL)         // 3125
#define NBIN 32                  // fine y-bins per polarity (8 rows each)
#define CAP 2048                 // per-region capacity (expect ~1562, +12 sigma)
#define F32EPS 1.1920929e-7f
#define SCALE 524288.0f          // 2^19 fixed-point for num
#define INV_SCALE (1.0f/524288.0f)

typedef unsigned long long u64;
typedef unsigned int u32;

// ws layout (bytes):
//   0           bins: uint2[8*64 regions][2048]      8,388,608
//   8,388,608   cursors: int[512]                    2,048  } single memset-0 (2176 B)
//   8,390,656   trefMax: u32[16]  (bm = b*2+m)       64     } (max of t bits)
//   8,390,720   negMin:  u32[16]                     64     } (max of ~t bits == min t)
//   8,390,784   flowI: float2[696,320]               5,570,560
//   13,961,344  fi0P: u64[32 g][8 sl][1024]          2,097,152
//   16,058,496  fi1P: u64[32 g][8 sl][4096]          8,388,608
#define OFF_CURS  8388608
#define OFF_TMAX  8390656
#define OFF_TMIN  8390720
#define OFF_FLOWI 8390784
#define OFF_FI0P  13961344
#define OFF_FI1P  16058496

__device__ __forceinline__ void lds_add64(u64* p, u64 v) {
    __hip_atomic_fetch_add(p, v, __ATOMIC_RELAXED, __HIP_MEMORY_SCOPE_WORKGROUP);
}
__device__ __forceinline__ int lds_add32(int* p, int v) {
    return __hip_atomic_fetch_add(p, v, __ATOMIC_RELAXED, __HIP_MEMORY_SCOPE_WORKGROUP);
}

// =============== prep: binning (0..255) + flow transpose (256..1023) + out zero ===============
__global__ __launch_bounds__(256) void k_prep(
    const int* __restrict__ xs, const int* __restrict__ ys,
    const float* __restrict__ ts, const int* __restrict__ ps,
    const float* __restrict__ f0, const float* __restrict__ f1,
    const float* __restrict__ f2, const float* __restrict__ f3,
    int* __restrict__ cursors, u32* __restrict__ negMin, u32* __restrict__ trefMax,
    uint2* __restrict__ bins, float2* __restrict__ flowI, float* __restrict__ out) {
    int bid = blockIdx.x;
    int tid = threadIdx.x;

    if (bid < 256) {
        // ---- binning into 64 fine regions per batch ----
        int b = bid & 7;
        int sl = bid >> 3;
        int w = tid >> 6, lane = tid & 63;

        const int*   xb = xs + b * NEV + sl * SLEV;
        const int*   yb = ys + b * NEV + sl * SLEV;
        const float* tb = ts + b * NEV + sl * SLEV;
        const int*   pb = ps + b * NEV + sl * SLEV;

        __shared__ int hist[4][64];
        __shared__ int curs[4][64];
        if (tid < 256) hist[tid >> 6][tid & 63] = 0;
        __syncthreads();

        float mnP = 2.0f, mxP = -1.0f, mnN = 2.0f, mxN = -1.0f;
        for (int i = w * 64 + lane; i < SLEV; i += 256) {
            int p = pb[i];
            int y = yb[i];
            float t = tb[i];
            int m = (p == 1) ? 0 : 1;
            lds_add32(&hist[w][m * 32 + (y >> 3)], 1);
            if (m == 0) { mnP = fminf(mnP, t); mxP = fmaxf(mxP, t); }
            else        { mnN = fminf(mnN, t); mxN = fmaxf(mxN, t); }
        }
        for (int o = 32; o > 0; o >>= 1) {
            mnP = fminf(mnP, __shfl_down(mnP, o, 64));
            mxP = fmaxf(mxP, __shfl_down(mxP, o, 64));
            mnN = fminf(mnN, __shfl_down(mnN, o, 64));
            mxN = fmaxf(mxN, __shfl_down(mxN, o, 64));
        }
        if (lane == 0) {
            if (mxP >= 0.0f) {
                atomicMax(&negMin[b * 2 + 0], ~__float_as_uint(mnP));
                atomicMax(&trefMax[b * 2 + 0], __float_as_uint(mxP));
            }
            if (mxN >= 0.0f) {
                atomicMax(&negMin[b * 2 + 1], ~__float_as_uint(mnN));
                atomicMax(&trefMax[b * 2 + 1], __float_as_uint(mxN));
            }
        }
        __syncthreads();
        if (tid < 64) {
            int tot = hist[0][tid] + hist[1][tid] + hist[2][tid] + hist[3][tid];
            int base = atomicAdd(&cursors[b * 64 + tid], tot);  // device-scope
            int run = base;
            #pragma unroll
            for (int w2 = 0; w2 < 4; ++w2) { curs[w2][tid] = run; run += hist[w2][tid]; }
        }
        __syncthreads();
        for (int i = w * 64 + lane; i < SLEV; i += 256) {
            int p = pb[i];
            int x = xb[i];
            int y = yb[i];
            float t = tb[i];
            int m = (p == 1) ? 0 : 1;
            int bin = m * 32 + (y >> 3);
            int off = lds_add32(&curs[w][bin], 1);
            if (off < CAP)
                bins[(size_t)(b * 64 + bin) * CAP + off] =
                    make_uint2((u32)(x | (y << 8)), __float_as_uint(t));
        }
        return;
    }

    if (bid == 256 && tid == 0) out[0] = 0.0f;

    // ---- flow transpose to interleaved float2 (768 blocks) ----
    const int nTot = 696320;
    for (int idx = (bid - 256) * 256 + tid; idx < nTot; idx += 768 * 256) {
        const float* src; int n, base, local = idx;
        if (idx < 8192)        { src = f0; n = 1024;  base = 0;      }
        else if (idx < 40960)  { src = f1; n = 4096;  base = 8192;   local = idx - 8192; }
        else if (idx < 172032) { src = f2; n = 16384; base = 40960;  local = idx - 40960; }
        else                   { src = f3; n = 65536; base = 172032; local = idx - 172032; }
        int b = local / n;
        int i = local - b * n;
        float2 v;
        v.x = src[(size_t)b * 2 * n + i];
        v.y = src[(size_t)b * 2 * n + n + i];
        flowI[base + local] = v;
    }
}

// =============== splat + misc, one grid ===============
// 1472 blocks x 512 thr.
//   bid 0..191 : misc (weight decay + smoothness)
//   bid 192+   : splat: sb=bid-192; b=sb&7; r=sb>>3 (0..159): m=r&1, dir=(r>>1)&1, role=r>>2
//     role 0..7  : fi2 chunk c (16 grid rows of 128), fine bins 4c-2..4c+5, finalize
//     role 8..23 : fi3 chunk c (16 grid rows of 256), fine bins 2c-1..2c+2, finalize
//     role 24..31: fi0 slice s: bins {s,s+8,s+16,s+24}, 4 replicas 32x32 -> fi0P
//     role 32..39: fi1 slice s: bins {s,s+8,s+16,s+24}, 64x64 grid -> fi1P
// max vertical displacement |t_*fy| <= ~5.5 grid rows < halos (8 rows fi3, 8 fi2-rows).
__global__ __launch_bounds__(512) void k_splat2(
    const float2* __restrict__ flowI,
    const uint2* __restrict__ bins, const int* __restrict__ cursors,
    const u32* __restrict__ negMin, const u32* __restrict__ trefMax,
    const float* __restrict__ params, int nP,
    const float* __restrict__ f0, const float* __restrict__ f1,
    const float* __restrict__ f2, const float* __restrict__ f3,
    u64* __restrict__ fi0P, u64* __restrict__ fi1P,
    float* __restrict__ out) {
    __shared__ u64 acc[4096];   // 32 KB
    __shared__ float red[8];

    int tid = threadIdx.x;
    int bid = blockIdx.x;

    if (bid < 192) {
        // ---- misc: weight decay + smoothness ----
        int gtid = bid * 512 + tid;
        int gstride = 192 * 512;
        float s = 0.0f;

        int n4 = nP >> 2;
        const float4* p4 = (const float4*)params;
        float wsum = 0.0f;
        for (int i = gtid; i < n4; i += gstride) {
            float4 v = p4[i];
            wsum += v.x * v.x + v.y * v.y + v.z * v.z + v.w * v.w;
        }
        if (gtid == 0) for (int i = n4 * 4; i < nP; ++i) wsum += params[i] * params[i];
        s += wsum * 5e-5f;

        const int nTot = 1392640;
        for (int idx = gtid; idx < nTot; idx += gstride) {
            int fi, off, logW;
            if (idx < 16384)       { fi = 0; off = 0;      logW = 5; }
            else if (idx < 81920)  { fi = 1; off = 16384;  logW = 6; }
            else if (idx < 344064) { fi = 2; off = 81920;  logW = 7; }
            else                   { fi = 3; off = 344064; logW = 8; }
            const float* f = (fi == 0) ? f0 : (fi == 1) ? f1 : (fi == 2) ? f2 : f3;
            int W = 1 << logW;
            int local = idx - off;
            int x = local & (W - 1);
            int y = (local >> logW) & (W - 1);
            float c_lr = 6.25f / (float)(16 * W * (W - 1));
            float c_dd = 6.25f / (float)(16 * (W - 1) * (W - 1));
            float v = f[local];
            bool xok = x < W - 1;
            bool yok = y < W - 1;
            float vr = xok ? f[local + 1] : 0.0f;
            float vd = yok ? f[local + W] : 0.0f;
            if (xok) { float d = vr - v; s += c_lr * __powf(d * d + 1e-6f, 0.45f); }
            if (yok) { float d = vd - v; s += c_lr * __powf(d * d + 1e-6f, 0.45f); }
            if (xok && yok) {
                float d1 = f[local + W + 1] - v;
                s += c_dd * __powf(d1 * d1 + 1e-6f, 0.45f);
                float d2 = vr - vd;
                s += c_dd * __powf(d2 * d2 + 1e-6f, 0.45f);
            }
        }

        for (int o = 32; o > 0; o >>= 1) s += __shfl_down(s, o, 64);
        if ((tid & 63) == 0) red[tid >> 6] = s;
        __syncthreads();
        if (tid == 0) {
            float tot = 0.0f;
            for (int w2 = 0; w2 < 8; ++w2) tot += red[w2];
            atomicAdd(out, tot);
        }
        return;
    }

    int sb = bid - 192;
    int b = sb & 7;
    int r = sb >> 3;
    int m = r & 1;
    int dir = (r >> 1) & 1;
    int role = r >> 2;
    int bm = b * 2 + m;

    int fi, row0 = 0, nrows = 0, lo = 0, hi = 0, slice = 0, mode;
    if (role < 8)       { int c = role;      fi = 2; mode = 1; row0 = 16 * c; nrows = 16;
                          lo = max(0, 4 * c - 2); hi = min(31, 4 * c + 5); }
    else if (role < 24) { int c = role - 8;  fi = 3; mode = 1; row0 = 16 * c; nrows = 16;
                          lo = max(0, 2 * c - 1); hi = min(31, 2 * c + 2); }
    else if (role < 32) { fi = 0; mode = 0; slice = role - 24; }
    else                { fi = 1; mode = 0; slice = role - 32; }

    int W = 32 << fi;
    int sh = 3 - fi;
    int rowEnd = row0 + nrows;
    float Wm1 = (float)(W - 1);
    int usedN = (fi == 2) ? 2048 : 4096;

    int fiB = (fi == 0) ? b * 1024
            : (fi == 1) ? 8192 + b * 4096
            : (fi == 2) ? 40960 + b * 16384
                        : 172032 + b * 65536;

    for (int i = tid; i < 4096; i += 512) acc[i] = 0ULL;
    __syncthreads();

    float trX = dir ? __uint_as_float(~negMin[bm]) : __uint_as_float(trefMax[bm]);
    float epsA = dir ? -F32EPS : F32EPS;

    int rep = (fi == 0) ? (((tid >> 4) & 3) << 10) : 0;

    int blist[8];
    int nb;
    if (mode == 0) { nb = 4; blist[0] = slice; blist[1] = slice + 8;
                     blist[2] = slice + 16; blist[3] = slice + 24; }
    else { nb = hi - lo + 1; for (int q = 0; q < nb; ++q) blist[q] = lo + q; }

    auto finish = [&](int xi, int yi, float t, float2 fv) {
        float t_ = trX - t + epsA;
        float x_ = fminf(fmaxf((float)xi + t_ * fv.x, 0.0f), Wm1);
        float y_ = fminf(fmaxf((float)yi + t_ * fv.y, 0.0f), Wm1);
        float x0f = floorf(x_), y0f = floorf(y_);
        float x0w = x_ - x0f, x1w = 1.0f - x0w;
        float y0w = y_ - y0f, y1w = 1.0f - y0w;
        int x0i = (int)x0f, y0i = (int)y0f;
        int x1i = min(x0i + 1, W - 1);
        int y1i = min(y0i + 1, W - 1);
        float tS = t * SCALE;
        u64 Pa = (1ULL << 32) | (u64)(u32)(x0w * y0w * tS);  // (x1i,y1i)
        u64 Pb = (1ULL << 32) | (u64)(u32)(x1w * y0w * tS);  // (x0i,y1i)
        u64 Pc = (1ULL << 32) | (u64)(u32)(x0w * y1w * tS);  // (x1i,y0i)
        u64 Pd = (1ULL << 32) | (u64)(u32)(x1w * y1w * tS);  // (x0i,y0i)
        if (mode == 0) {
            int r1 = rep + y1i * W;
            int r0 = rep + y0i * W;
            lds_add64(&acc[r1 + x1i], Pa);
            lds_add64(&acc[r1 + x0i], Pb);
            lds_add64(&acc[r0 + x1i], Pc);
            lds_add64(&acc[r0 + x0i], Pd);
        } else {
            if (y1i >= row0 && y1i < rowEnd) {
                int rr = (y1i - row0) * W;
                lds_add64(&acc[rr + x1i], Pa);
                lds_add64(&acc[rr + x0i], Pb);
            }
            if (y0i >= row0 && y0i < rowEnd) {
                int rr = (y0i - row0) * W;
                lds_add64(&acc[rr + x1i], Pc);
                lds_add64(&acc[rr + x0i], Pd);
            }
        }
    };

    for (int q = 0; q < nb; ++q) {
        int region = b * 64 + m * 32 + blist[q];
        int cnt = min(cursors[region], CAP);
        const uint2* eb = bins + (size_t)region * CAP;
        int i = tid;
        for (; i + 512 < cnt; i += 1024) {
            uint2 e1 = eb[i];
            uint2 e2 = eb[i + 512];
            int xi1 = (e1.x & 255) >> sh, yi1 = ((e1.x >> 8) & 255) >> sh;
            int xi2 = (e2.x & 255) >> sh, yi2 = ((e2.x >> 8) & 255) >> sh;
            float2 fv1 = flowI[fiB + yi1 * W + xi1];
            float2 fv2 = flowI[fiB + yi2 * W + xi2];
            finish(xi1, yi1, __uint_as_float(e1.y), fv1);
            finish(xi2, yi2, __uint_as_float(e2.y), fv2);
        }
        if (i < cnt) {
            uint2 e1 = eb[i];
            int xi1 = (e1.x & 255) >> sh, yi1 = ((e1.x >> 8) & 255) >> sh;
            float2 fv1 = flowI[fiB + yi1 * W + xi1];
            finish(xi1, yi1, __uint_as_float(e1.y), fv1);
        }
    }
    __syncthreads();

    if (mode == 0) {
        int g = bm * 2 + dir;
        if (fi == 0) {
            for (int j = tid; j < 1024; j += 512)
                fi0P[(size_t)(g * 8 + slice) * 1024 + j] =
                    acc[j] + acc[j + 1024] + acc[j + 2048] + acc[j + 3072];
        } else {
            for (int j = tid; j < 4096; j += 512)
                fi1P[(size_t)(g * 8 + slice) * 4096 + j] = acc[j];
        }
        return;
    }

    float s = 0.0f;
    for (int j = tid; j < usedN; j += 512) {
        u64 v = acc[j];
        float num = (float)(u32)(v & 0xffffffffULL) * INV_SCALE;
        float den = (float)(u32)(v >> 32);
        float rr = num / (den + F32EPS);
        s += sqrtf(rr * rr + 1e-6f);
    }
    for (int o = 32; o > 0; o >>= 1) s += __shfl_down(s, o, 64);
    if ((tid & 63) == 0) red[tid >> 6] = s;
    __syncthreads();
    if (tid == 0) {
        float tot = 0.0f;
        for (int w2 = 0; w2 < 8; ++w2) tot += red[w2];
        atomicAdd(out, tot);
    }
}

// =============== tail: merge fi0/fi1 partials ===============
__global__ __launch_bounds__(256) void k_tail(
    const u64* __restrict__ fi0P, const u64* __restrict__ fi1P,
    float* __restrict__ out) {
    int gtid = blockIdx.x * 256 + threadIdx.x;
    u64 v = 0;
    if (gtid < 32768) {
        int g = gtid >> 10, j = gtid & 1023;
        const u64* p = fi0P + (size_t)(g * 8) * 1024 + j;
        #pragma unroll
        for (int k = 0; k < 8; ++k) v += p[k * 1024];
    } else {
        int rr = gtid - 32768;
        int g = rr >> 12, j = rr & 4095;
        const u64* p = fi1P + (size_t)(g * 8) * 4096 + j;
        #pragma unroll
        for (int k = 0; k < 8; ++k) v += p[k * 4096];
    }
    float num = (float)(u32)(v & 0xffffffffULL) * INV_SCALE;
    float den = (float)(u32)(v >> 32);
    float rr = num / (den + F32EPS);
    float s = sqrtf(rr * rr + 1e-6f);
    for (int o = 32; o > 0; o >>= 1) s += __shfl_down(s, o, 64);
    __shared__ float red[4];
    if ((threadIdx.x & 63) == 0) red[threadIdx.x >> 6] = s;
    __syncthreads();
    if (threadIdx.x == 0)
        atomicAdd(out, red[0] + red[1] + red[2] + red[3]);
}

extern "C" void kernel_launch(void* const* d_in, const int* in_sizes, int n_in,
                              void* d_out, int out_size, void* d_ws, size_t ws_size,
                              hipStream_t stream) {
    const float* f0 = (const float*)d_in[0];
    const float* f1 = (const float*)d_in[1];
    const float* f2 = (const float*)d_in[2];
    const float* f3 = (const float*)d_in[3];
    const int*   xs = (const int*)d_in[4];
    const int*   ys = (const int*)d_in[5];
    const float* ts = (const float*)d_in[6];
    const int*   ps = (const int*)d_in[7];
    const float* params = (const float*)d_in[10];
    float* out = (float*)d_out;

    char* ws = (char*)d_ws;
    uint2*  bins    = (uint2*)ws;
    int*    cursors = (int*)(ws + OFF_CURS);
    u32*    trefMax = (u32*)(ws + OFF_TMAX);
    u32*    negMin  = (u32*)(ws + OFF_TMIN);
    float2* flowI   = (float2*)(ws + OFF_FLOWI);
    u64*    fi0P    = (u64*)(ws + OFF_FI0P);
    u64*    fi1P    = (u64*)(ws + OFF_FI1P);

    // single memset: cursors (2048) + trefMax (64) + negMin (64)
    hipMemsetAsync(ws + OFF_CURS, 0, 2176, stream);

    hipLaunchKernelGGL(k_prep, dim3(1024), dim3(256), 0, stream,
                       xs, ys, ts, ps, f0, f1, f2, f3,
                       cursors, negMin, trefMax, bins, flowI, out);
    hipLaunchKernelGGL(k_splat2, dim3(1472), dim3(512), 0, stream,
                       flowI, bins, cursors, negMin, trefMax,
                       params, in_sizes[10], f0, f1, f2, f3,
                       fi0P, fi1P, out);
    hipLaunchKernelGGL(k_tail, dim3(640), dim3(256), 0, stream, fi0P, fi1P, out);
}